// Round 4
// baseline (1471.950 us; speedup 1.0000x reference)
//
#include <hip/hip_runtime.h>
#include <stdint.h>

#define NN 100000
#define NE 1600000
#define NB 4096
#define FIN 92
#define H 51
#define H3 153
#define TSTEPS 7
#define SCAN_B 391   // ceil(NN/256)

// ---------------- static device workspace (BSS; no hipMalloc) ----------------
__device__ float g_x1[(size_t)NN * 52 + 64];   // lrelu(x@W1+b1), row stride 52 (pad col = 0)
__device__ float g_xr[NN];                     // x1 @ att_r
__device__ float g_agg[(size_t)NN * H + 64];   // softmax-weighted sum of lrelu(xe) per dst
__device__ float g_x2[(size_t)NN * H + 64];    // node state after GRU1 + relu
__device__ float g_xl[(size_t)NN * H + 64];    // x2 @ Wm
__device__ float g_al[NN];                     // xl @ att_src
__device__ int   g_gs[NB + 2];                 // graph start offsets (batch is sorted)
__device__ float g_wg1[H * H * 8];             // GRU1 weights interleaved [k][j][8]
__device__ float g_bg1[64 * 8];
__device__ float g_wg2[H * H * 8];
__device__ float g_bg2[64 * 8];
__device__ float g_wv[64];                     // Wm @ att_dst
// CSR scratch
__device__ int   g_cnt[NN];
__device__ int   g_rp[NN + 1];
__device__ int   g_cur[NN];
__device__ int   g_src[NE + 2];                // src node id, grouped by dst
__device__ float g_eac[(size_t)NE * 12 + 16];  // edge_attr rows in CSR order, padded to 12 floats
__device__ int   g_bsum[512];
__device__ int   g_boff[512];

__device__ __forceinline__ float lrelu(float v) { return v > 0.f ? v : 0.01f * v; }
__device__ __forceinline__ float elu1(float v) { return v > 0.f ? v : expm1f(v); }
__device__ __forceinline__ float sigm(float v) { return 1.f / (1.f + __expf(-v)); }

__device__ __forceinline__ float wave_sum(float v) {
    v += __shfl_xor(v, 32, 64);
    v += __shfl_xor(v, 16, 64);
    v += __shfl_xor(v, 8, 64);
    v += __shfl_xor(v, 4, 64);
    v += __shfl_xor(v, 2, 64);
    v += __shfl_xor(v, 1, 64);
    return v;
}
__device__ __forceinline__ void wave_sum2(float& a, float& b) {
    a += __shfl_xor(a, 32, 64); b += __shfl_xor(b, 32, 64);
    a += __shfl_xor(a, 16, 64); b += __shfl_xor(b, 16, 64);
    a += __shfl_xor(a, 8, 64);  b += __shfl_xor(b, 8, 64);
    a += __shfl_xor(a, 4, 64);  b += __shfl_xor(b, 4, 64);
    a += __shfl_xor(a, 2, 64);  b += __shfl_xor(b, 2, 64);
    a += __shfl_xor(a, 1, 64);  b += __shfl_xor(b, 1, 64);
}

// ---------------- prep ----------------
__global__ __launch_bounds__(256) void k_zero() {
    int i = blockIdx.x * 256 + threadIdx.x;
    if (i < NN) g_cnt[i] = 0;
}

__global__ void k_pack_gru(const float* __restrict__ Wih, const float* __restrict__ bih,
                           const float* __restrict__ Whh, const float* __restrict__ bhh, int which) {
    int kj = blockIdx.x * 256 + threadIdx.x;
    if (kj >= H * H) return;
    float* Wg = which ? g_wg2 : g_wg1;
    float* bg = which ? g_bg2 : g_bg1;
    int k = kj / H, j = kj - k * H;
    float* o = Wg + (size_t)kj * 8;
    o[0] = Wih[k * H3 + j];
    o[1] = Wih[k * H3 + H + j];
    o[2] = Wih[k * H3 + 2 * H + j];
    o[3] = Whh[k * H3 + j];
    o[4] = Whh[k * H3 + H + j];
    o[5] = Whh[k * H3 + 2 * H + j];
    o[6] = 0.f; o[7] = 0.f;
    if (kj < H) {
        float* ob = bg + (size_t)kj * 8;
        ob[0] = bih[kj]; ob[1] = bih[H + kj]; ob[2] = bih[2 * H + kj];
        ob[3] = bhh[kj]; ob[4] = bhh[H + kj]; ob[5] = bhh[2 * H + kj];
        ob[6] = 0.f; ob[7] = 0.f;
    }
}

__global__ void k_wv(const float* __restrict__ Wm, const float* __restrict__ ad) {
    int k = threadIdx.x;
    if (k >= 64) return;
    float a = 0.f;
    if (k < H) for (int j = 0; j < H; ++j) a = fmaf(Wm[k * H + j], ad[j], a);
    g_wv[k] = a;
}

__global__ void k_gstart(const int* __restrict__ batch) {
    int n = blockIdx.x * 256 + threadIdx.x;
    if (n >= NN) return;
    int bn = batch[n];
    int bp = (n == 0) ? -1 : batch[n - 1];
    for (int b = bp + 1; b <= bn; ++b) g_gs[b] = n;
    if (n == NN - 1) for (int b = bn + 1; b <= NB; ++b) g_gs[b] = NN;
}

// ---------------- CSR build ----------------
__global__ __launch_bounds__(256) void k_count(const int* __restrict__ ei) {
    int e = blockIdx.x * 256 + threadIdx.x;
    if (e >= NE) return;
    atomicAdd(&g_cnt[ei[NE + e]], 1);
}

__global__ __launch_bounds__(256) void k_scan1() {
    __shared__ int sm[256];
    int tid = threadIdx.x;
    int i = blockIdx.x * 256 + tid;
    sm[tid] = (i < NN) ? g_cnt[i] : 0;
    __syncthreads();
#pragma unroll
    for (int off = 1; off < 256; off <<= 1) {
        int t = (tid >= off) ? sm[tid - off] : 0;
        __syncthreads();
        sm[tid] += t;
        __syncthreads();
    }
    if (i < NN) g_rp[i + 1] = sm[tid];
    if (tid == 255) g_bsum[blockIdx.x] = sm[255];
}

__global__ void k_scan2() {
    __shared__ int sm[512];
    int tid = threadIdx.x;
    sm[tid] = (tid < SCAN_B) ? g_bsum[tid] : 0;
    __syncthreads();
#pragma unroll
    for (int off = 1; off < 512; off <<= 1) {
        int t = (tid >= off) ? sm[tid - off] : 0;
        __syncthreads();
        sm[tid] += t;
        __syncthreads();
    }
    if (tid < SCAN_B) g_boff[tid] = (tid == 0) ? 0 : sm[tid - 1];
}

__global__ __launch_bounds__(256) void k_scan3() {
    int i = blockIdx.x * 256 + threadIdx.x;
    if (i >= NN) return;
    int v = g_rp[i + 1] + g_boff[blockIdx.x];
    g_rp[i + 1] = v;
    if (i == 0) { g_rp[0] = 0; g_cur[0] = 0; }
    if (i + 1 < NN) g_cur[i + 1] = v;
}

__global__ __launch_bounds__(256) void k_fill(const int* __restrict__ ei, const float* __restrict__ ea) {
    int e = blockIdx.x * 256 + threadIdx.x;
    if (e >= NE) return;
    int d = ei[NE + e];
    int pos = atomicAdd(&g_cur[d], 1);
    g_src[pos] = ei[e];
    const float2* s2 = (const float2*)(ea + (size_t)e * 10);
    float2 v0 = s2[0], v1 = s2[1], v2 = s2[2], v3 = s2[3], v4 = s2[4];
    float* dst = g_eac + (size_t)pos * 12;
    float2* d2 = (float2*)dst;
    d2[0] = v0; d2[1] = v1; d2[2] = v2; d2[3] = v3; d2[4] = v4;
    d2[5] = make_float2(0.f, 0.f);
}

// ---------------- lin1: x1 = lrelu(x@W1+b1), xr = x1@att_r ----------------
__global__ __launch_bounds__(256, 4) void k_lin1(const float* __restrict__ x, const float* __restrict__ W1,
                                                 const float* __restrict__ b1, const float* __restrict__ attr_) {
    int n = blockIdx.x * 256 + threadIdx.x;
    if (n >= NN) return;
    const float4* xq4 = (const float4*)(x + (size_t)n * FIN);
    float acc[H];
#pragma unroll
    for (int h = 0; h < H; ++h) acc[h] = 0.f;
#pragma unroll 1
    for (int q = 0; q < FIN / 4; ++q) {
        float4 v = xq4[q];
        const float* wr = W1 + (4 * q) * H;
#pragma unroll
        for (int h = 0; h < H; ++h)
            acc[h] = fmaf(v.x, wr[h], fmaf(v.y, wr[H + h], fmaf(v.z, wr[2 * H + h], fmaf(v.w, wr[3 * H + h], acc[h]))));
    }
    float xrv = 0.f;
    float* xo = g_x1 + (size_t)n * 52;
#pragma unroll
    for (int h = 0; h < H; ++h) {
        float v = lrelu(acc[h] + b1[h]);
        xo[h] = v;
        xrv = fmaf(v, attr_[h], xrv);
    }
    xo[H] = 0.f;
    g_xr[n] = xrv;
}

// ---------------- GATEConv, single pass: wave per dst node, lane = channel ----------------
__global__ __launch_bounds__(256, 3) void k_gate(const float* __restrict__ We1, const float* __restrict__ attl) {
    int lane = threadIdx.x & 63;
    int lj = lane < H ? lane : H - 1;
    int n0 = blockIdx.x * 4 + (threadIdx.x >> 6);
    if (n0 >= NN) return;
    int n = __builtin_amdgcn_readfirstlane(n0);
    float wcol[64];
#pragma unroll
    for (int k = 0; k < H; ++k) wcol[k] = We1[k * H + lj];
    wcol[51] = 0.f;
#pragma unroll
    for (int p = 0; p < 10; ++p) wcol[52 + p] = We1[(H + p) * H + lj];
    wcol[62] = 0.f; wcol[63] = 0.f;
    float attlv = attl[lj];
    float xrd = g_xr[n];
    int rs = g_rp[n], re = g_rp[n + 1];
    float accH = 0.f, den = 0.f;
    int idx = rs;
    for (; idx + 2 <= re; idx += 2) {
        int s0 = __builtin_amdgcn_readfirstlane(g_src[idx]);
        int s1 = __builtin_amdgcn_readfirstlane(g_src[idx + 1]);
        const float4* xa = (const float4*)(g_x1 + (size_t)s0 * 52);
        const float4* xb = (const float4*)(g_x1 + (size_t)s1 * 52);
        const float4* e4a = (const float4*)(g_eac + (size_t)idx * 12);
        const float4* e4b = (const float4*)(g_eac + (size_t)(idx + 1) * 12);
        float xe0 = 0.f, xe1 = 0.f;
#pragma unroll
        for (int q = 0; q < 13; ++q) {
            float4 va = xa[q], vb = xb[q];
            xe0 = fmaf(va.x, wcol[4 * q], fmaf(va.y, wcol[4 * q + 1],
                  fmaf(va.z, wcol[4 * q + 2], fmaf(va.w, wcol[4 * q + 3], xe0))));
            xe1 = fmaf(vb.x, wcol[4 * q], fmaf(vb.y, wcol[4 * q + 1],
                  fmaf(vb.z, wcol[4 * q + 2], fmaf(vb.w, wcol[4 * q + 3], xe1))));
        }
#pragma unroll
        for (int q = 0; q < 3; ++q) {
            float4 va = e4a[q], vb = e4b[q];
            xe0 = fmaf(va.x, wcol[52 + 4 * q], fmaf(va.y, wcol[53 + 4 * q],
                  fmaf(va.z, wcol[54 + 4 * q], fmaf(va.w, wcol[55 + 4 * q], xe0))));
            xe1 = fmaf(vb.x, wcol[52 + 4 * q], fmaf(vb.y, wcol[53 + 4 * q],
                  fmaf(vb.z, wcol[54 + 4 * q], fmaf(vb.w, wcol[55 + 4 * q], xe1))));
        }
        float xl0 = lrelu(xe0), xl1 = lrelu(xe1);
        float a0 = (lane < H) ? xl0 * attlv : 0.f;
        float a1 = (lane < H) ? xl1 * attlv : 0.f;
        wave_sum2(a0, a1);
        float en0 = __expf(lrelu(a0 + xrd));
        float en1 = __expf(lrelu(a1 + xrd));
        accH = fmaf(en0, xl0, accH); den += en0;
        accH = fmaf(en1, xl1, accH); den += en1;
    }
    if (idx < re) {
        int s0 = __builtin_amdgcn_readfirstlane(g_src[idx]);
        const float4* xa = (const float4*)(g_x1 + (size_t)s0 * 52);
        const float4* e4a = (const float4*)(g_eac + (size_t)idx * 12);
        float xe0 = 0.f;
#pragma unroll
        for (int q = 0; q < 13; ++q) {
            float4 va = xa[q];
            xe0 = fmaf(va.x, wcol[4 * q], fmaf(va.y, wcol[4 * q + 1],
                  fmaf(va.z, wcol[4 * q + 2], fmaf(va.w, wcol[4 * q + 3], xe0))));
        }
#pragma unroll
        for (int q = 0; q < 3; ++q) {
            float4 va = e4a[q];
            xe0 = fmaf(va.x, wcol[52 + 4 * q], fmaf(va.y, wcol[53 + 4 * q],
                  fmaf(va.z, wcol[54 + 4 * q], fmaf(va.w, wcol[55 + 4 * q], xe0))));
        }
        float xl0 = lrelu(xe0);
        float a0 = wave_sum((lane < H) ? xl0 * attlv : 0.f);
        float en0 = __expf(lrelu(a0 + xrd));
        accH = fmaf(en0, xl0, accH); den += en0;
    }
    if (lane < H) g_agg[(size_t)n * H + lane] = accH / (den + 1e-16f);
}

// ---------------- gate(We2) + GRU1 + xl/al fused: wave per node ----------------
__global__ __launch_bounds__(256) void k_gategru(const float* __restrict__ We2, const float* __restrict__ gb,
                                                 const float* __restrict__ Wm, const float* __restrict__ asrc) {
    int lane = threadIdx.x & 63;
    int lj = lane < H ? lane : H - 1;
    int n0 = blockIdx.x * 4 + (threadIdx.x >> 6);
    if (n0 >= NN) return;
    int n = __builtin_amdgcn_readfirstlane(n0);
    const float* aggr = g_agg + (size_t)n * H;
    const float* x1r = g_x1 + (size_t)n * 52;
    float acc = 0.f;
    for (int k = 0; k < H; ++k) acc = fmaf(aggr[k], We2[k * H + lj], acc);
    float hb = elu1(acc + gb[lj]);
    float gir = 0, giz = 0, gin = 0, ghr = 0, ghz = 0, ghn = 0;
    for (int k = 0; k < H; ++k) {
        float hbk = __shfl(hb, k, 64);
        float xk = x1r[k];
        const float4* wp = (const float4*)(g_wg1 + ((size_t)(k * H + lj)) * 8);
        float4 w0 = wp[0];
        float4 w1 = wp[1];
        gir = fmaf(hbk, w0.x, gir); giz = fmaf(hbk, w0.y, giz); gin = fmaf(hbk, w0.z, gin);
        ghr = fmaf(xk, w0.w, ghr);  ghz = fmaf(xk, w1.x, ghz);  ghn = fmaf(xk, w1.y, ghn);
    }
    const float4* bp = (const float4*)(g_bg1 + lane * 8);
    float4 b0 = bp[0];
    float4 b1v = bp[1];
    float r = sigm(gir + b0.x + ghr + b0.w);
    float z = sigm(giz + b0.y + ghz + b1v.x);
    float nn2 = tanhf(gin + b0.z + r * (ghn + b1v.y));
    float xj = x1r[lane];
    float o2 = fmaxf((1.f - z) * nn2 + z * xj, 0.f);
    if (lane < H) g_x2[(size_t)n * H + lane] = o2;
    // xl = x2row @ Wm, al = xl @ att_src
    float xlacc = 0.f;
    for (int k = 0; k < H; ++k) {
        float xk = __shfl(o2, k, 64);
        xlacc = fmaf(xk, Wm[k * H + lj], xlacc);
    }
    if (lane < H) g_xl[(size_t)n * H + lane] = xlacc;
    float v = (lane < H) ? xlacc * asrc[lj] : 0.f;
    v = wave_sum(v);
    if (lane == 0) g_al[n] = v;
}

// ---------------- readout + all 7 timesteps + final linear: wave per graph ----------------
__global__ __launch_bounds__(256) void k_mol_all(const float* __restrict__ mb, const float* __restrict__ W2,
                                                 const float* __restrict__ b2, float* __restrict__ dout) {
    int lane = threadIdx.x & 63;
    int lj = lane < H ? lane : H - 1;
    int b = __builtin_amdgcn_readfirstlane(blockIdx.x * 4 + (threadIdx.x >> 6));
    int gs = g_gs[b], ge = g_gs[b + 1];
    // readout: out0 = relu(sum x2 rows)
    float oj = 0.f;
    for (int i = gs; i < ge; ++i) oj += g_x2[(size_t)i * H + lane];
    oj = fmaxf(oj, 0.f);
    float wvl = g_wv[lane];
    float mbl = mb[lj];
#pragma unroll 1
    for (int t = 0; t < TSTEPS; ++t) {
        float arb = wave_sum((lane < H) ? oj * wvl : 0.f);
        // softmax denom
        float ssum = 0.f;
        for (int base = gs; base < ge; base += 64) {
            int i = base + lane;
            float ev = (i < ge) ? __expf(lrelu(g_al[i] + arb)) : 0.f;
            ssum += ev;
        }
        ssum = wave_sum(ssum);
        float inv = 1.f / (ssum + 1e-16f);
        // weighted sum of xl rows
        float acc = 0.f;
        for (int i = gs; i < ge; ++i) {
            float evi = __expf(lrelu(g_al[i] + arb));
            acc = fmaf(evi * inv, g_xl[(size_t)i * H + lane], acc);
        }
        float hm = elu1(acc + mbl);
        // GRU2
        float gir = 0, giz = 0, gin = 0, ghr = 0, ghz = 0, ghn = 0;
        for (int k = 0; k < H; ++k) {
            float hmk = __shfl(hm, k, 64);
            float ok = __shfl(oj, k, 64);
            const float4* wp = (const float4*)(g_wg2 + ((size_t)(k * H + lj)) * 8);
            float4 w0 = wp[0];
            float4 w1 = wp[1];
            gir = fmaf(hmk, w0.x, gir); giz = fmaf(hmk, w0.y, giz); gin = fmaf(hmk, w0.z, gin);
            ghr = fmaf(ok, w0.w, ghr);  ghz = fmaf(ok, w1.x, ghz);  ghn = fmaf(ok, w1.y, ghn);
        }
        const float4* bp = (const float4*)(g_bg2 + lane * 8);
        float4 b0 = bp[0];
        float4 b1v = bp[1];
        float r = sigm(gir + b0.x + ghr + b0.w);
        float z = sigm(giz + b0.y + ghz + b1v.x);
        float nn2 = tanhf(gin + b0.z + r * (ghn + b1v.y));
        oj = fmaxf((1.f - z) * nn2 + z * oj, 0.f);
    }
    float fv = wave_sum((lane < H) ? oj * W2[lj] : 0.f);
    if (lane == 0) dout[b] = fv + b2[0];
}

extern "C" void kernel_launch(void* const* d_in, const int* in_sizes, int n_in,
                              void* d_out, int out_size, void* d_ws, size_t ws_size,
                              hipStream_t stream) {
    const float* x     = (const float*)d_in[0];
    const int*   ei    = (const int*)d_in[1];
    const float* ea    = (const float*)d_in[2];
    const int*   batch = (const int*)d_in[3];
    const float* W1    = (const float*)d_in[4];
    const float* b1    = (const float*)d_in[5];
    const float* We1   = (const float*)d_in[6];
    const float* attl  = (const float*)d_in[7];
    const float* attr_ = (const float*)d_in[8];
    const float* We2   = (const float*)d_in[9];
    const float* gb    = (const float*)d_in[10];
    const float* Wm    = (const float*)d_in[15];
    const float* asrc  = (const float*)d_in[16];
    const float* adst  = (const float*)d_in[17];
    const float* mb    = (const float*)d_in[18];
    const float* W2    = (const float*)d_in[23];
    const float* b2    = (const float*)d_in[24];
    float* dout = (float*)d_out;

    // CSR build
    k_zero<<<SCAN_B, 256, 0, stream>>>();
    k_count<<<NE / 256, 256, 0, stream>>>(ei);
    k_scan1<<<SCAN_B, 256, 0, stream>>>();
    k_scan2<<<1, 512, 0, stream>>>();
    k_scan3<<<SCAN_B, 256, 0, stream>>>();
    k_fill<<<NE / 256, 256, 0, stream>>>(ei, ea);

    // weight prep
    k_pack_gru<<<(H * H + 255) / 256, 256, 0, stream>>>((const float*)d_in[11], (const float*)d_in[12],
                                                        (const float*)d_in[13], (const float*)d_in[14], 0);
    k_pack_gru<<<(H * H + 255) / 256, 256, 0, stream>>>((const float*)d_in[19], (const float*)d_in[20],
                                                        (const float*)d_in[21], (const float*)d_in[22], 1);
    k_wv<<<1, 64, 0, stream>>>(Wm, adst);
    k_gstart<<<(NN + 255) / 256, 256, 0, stream>>>(batch);

    // main pipeline
    k_lin1<<<(NN + 255) / 256, 256, 0, stream>>>(x, W1, b1, attr_);
    k_gate<<<NN / 4, 256, 0, stream>>>(We1, attl);
    k_gategru<<<NN / 4, 256, 0, stream>>>(We2, gb, Wm, asrc);
    k_mol_all<<<NB / 4, 256, 0, stream>>>(mb, W2, b2, dout);
}

// Round 6
// 1251.255 us; speedup vs baseline: 1.1764x; 1.1764x over previous
//
#include <hip/hip_runtime.h>
#include <stdint.h>

#define NN 100000
#define NE 1600000
#define NB 4096
#define FIN 92
#define H 51
#define H3 153
#define TSTEPS 7
#define SCAN_B 391   // ceil(NN/256)

// ---------------- static device workspace (BSS; no hipMalloc) ----------------
__device__ float g_x1[(size_t)NN * 52 + 64];   // lrelu(x@W1+b1), row stride 52 (pad col = 0)
__device__ float g_xr[NN];                     // x1 @ att_r
__device__ float g_agg[(size_t)NN * H + 64];   // softmax-weighted sum of lrelu(xe) per dst
__device__ float g_x2[(size_t)NN * H + 64];    // node state after GRU1 + relu
__device__ float g_xl[(size_t)NN * H + 64];    // x2 @ Wm
__device__ float g_al[NN];                     // xl @ att_src
__device__ int   g_gs[NB + 2];                 // graph start offsets (batch is sorted)
__device__ float g_wg1[H * H * 8];             // GRU1 weights interleaved [k][j][8]
__device__ float g_bg1[64 * 8];
__device__ float g_wg2[H * H * 8];
__device__ float g_bg2[64 * 8];
__device__ float g_wv[64];                     // Wm @ att_dst
// CSR scratch
__device__ int   g_cnt[NN];
__device__ int   g_rp[NN + 1];
__device__ int   g_cur[NN];
__device__ int   g_src[NE + 4];                // src node id, grouped by dst
__device__ float g_eac[(size_t)NE * 12 + 16];  // edge_attr rows in CSR order, padded to 12 floats
__device__ int   g_bsum[512];
__device__ int   g_boff[512];

__device__ __forceinline__ float lrelu(float v) { return v > 0.f ? v : 0.01f * v; }
__device__ __forceinline__ float elu1(float v) { return v > 0.f ? v : expm1f(v); }
__device__ __forceinline__ float sigm(float v) { return 1.f / (1.f + __expf(-v)); }

__device__ __forceinline__ float wave_sum(float v) {
    v += __shfl_xor(v, 32, 64);
    v += __shfl_xor(v, 16, 64);
    v += __shfl_xor(v, 8, 64);
    v += __shfl_xor(v, 4, 64);
    v += __shfl_xor(v, 2, 64);
    v += __shfl_xor(v, 1, 64);
    return v;
}
__device__ __forceinline__ void wave_sum4(float& a, float& b, float& c, float& d) {
    a += __shfl_xor(a, 32, 64); b += __shfl_xor(b, 32, 64); c += __shfl_xor(c, 32, 64); d += __shfl_xor(d, 32, 64);
    a += __shfl_xor(a, 16, 64); b += __shfl_xor(b, 16, 64); c += __shfl_xor(c, 16, 64); d += __shfl_xor(d, 16, 64);
    a += __shfl_xor(a, 8, 64);  b += __shfl_xor(b, 8, 64);  c += __shfl_xor(c, 8, 64);  d += __shfl_xor(d, 8, 64);
    a += __shfl_xor(a, 4, 64);  b += __shfl_xor(b, 4, 64);  c += __shfl_xor(c, 4, 64);  d += __shfl_xor(d, 4, 64);
    a += __shfl_xor(a, 2, 64);  b += __shfl_xor(b, 2, 64);  c += __shfl_xor(c, 2, 64);  d += __shfl_xor(d, 2, 64);
    a += __shfl_xor(a, 1, 64);  b += __shfl_xor(b, 1, 64);  c += __shfl_xor(c, 1, 64);  d += __shfl_xor(d, 1, 64);
}

// dot4 helper — plain inline function, immune to macro member-name capture
__device__ __forceinline__ float d4(float acc, float4 t, float4 wv) {
    return fmaf(t.x, wv.x, fmaf(t.y, wv.y, fmaf(t.z, wv.z, fmaf(t.w, wv.w, acc))));
}

// ---------------- prep ----------------
__global__ __launch_bounds__(256) void k_zero() {
    int i = blockIdx.x * 256 + threadIdx.x;
    if (i < NN) g_cnt[i] = 0;
}

__global__ void k_pack_gru(const float* __restrict__ Wih, const float* __restrict__ bih,
                           const float* __restrict__ Whh, const float* __restrict__ bhh, int which) {
    int kj = blockIdx.x * 256 + threadIdx.x;
    if (kj >= H * H) return;
    float* Wg = which ? g_wg2 : g_wg1;
    float* bg = which ? g_bg2 : g_bg1;
    int k = kj / H, j = kj - k * H;
    float* o = Wg + (size_t)kj * 8;
    o[0] = Wih[k * H3 + j];
    o[1] = Wih[k * H3 + H + j];
    o[2] = Wih[k * H3 + 2 * H + j];
    o[3] = Whh[k * H3 + j];
    o[4] = Whh[k * H3 + H + j];
    o[5] = Whh[k * H3 + 2 * H + j];
    o[6] = 0.f; o[7] = 0.f;
    if (kj < H) {
        float* ob = bg + (size_t)kj * 8;
        ob[0] = bih[kj]; ob[1] = bih[H + kj]; ob[2] = bih[2 * H + kj];
        ob[3] = bhh[kj]; ob[4] = bhh[H + kj]; ob[5] = bhh[2 * H + kj];
        ob[6] = 0.f; ob[7] = 0.f;
    }
}

__global__ void k_wv(const float* __restrict__ Wm, const float* __restrict__ ad) {
    int k = threadIdx.x;
    if (k >= 64) return;
    float a = 0.f;
    if (k < H) for (int j = 0; j < H; ++j) a = fmaf(Wm[k * H + j], ad[j], a);
    g_wv[k] = a;
}

__global__ void k_gstart(const int* __restrict__ batch) {
    int n = blockIdx.x * 256 + threadIdx.x;
    if (n >= NN) return;
    int bn = batch[n];
    int bp = (n == 0) ? -1 : batch[n - 1];
    for (int b = bp + 1; b <= bn; ++b) g_gs[b] = n;
    if (n == NN - 1) for (int b = bn + 1; b <= NB; ++b) g_gs[b] = NN;
}

// ---------------- CSR build ----------------
__global__ __launch_bounds__(256) void k_count(const int* __restrict__ ei) {
    int e = blockIdx.x * 256 + threadIdx.x;
    if (e >= NE) return;
    atomicAdd(&g_cnt[ei[NE + e]], 1);
}

__global__ __launch_bounds__(256) void k_scan1() {
    __shared__ int sm[256];
    int tid = threadIdx.x;
    int i = blockIdx.x * 256 + tid;
    sm[tid] = (i < NN) ? g_cnt[i] : 0;
    __syncthreads();
#pragma unroll
    for (int off = 1; off < 256; off <<= 1) {
        int t = (tid >= off) ? sm[tid - off] : 0;
        __syncthreads();
        sm[tid] += t;
        __syncthreads();
    }
    if (i < NN) g_rp[i + 1] = sm[tid];
    if (tid == 255) g_bsum[blockIdx.x] = sm[255];
}

__global__ void k_scan2() {
    __shared__ int sm[512];
    int tid = threadIdx.x;
    sm[tid] = (tid < SCAN_B) ? g_bsum[tid] : 0;
    __syncthreads();
#pragma unroll
    for (int off = 1; off < 512; off <<= 1) {
        int t = (tid >= off) ? sm[tid - off] : 0;
        __syncthreads();
        sm[tid] += t;
        __syncthreads();
    }
    if (tid < SCAN_B) g_boff[tid] = (tid == 0) ? 0 : sm[tid - 1];
}

__global__ __launch_bounds__(256) void k_scan3() {
    int i = blockIdx.x * 256 + threadIdx.x;
    if (i >= NN) return;
    int v = g_rp[i + 1] + g_boff[blockIdx.x];
    g_rp[i + 1] = v;
    if (i == 0) { g_rp[0] = 0; g_cur[0] = 0; }
    if (i + 1 < NN) g_cur[i + 1] = v;
}

__global__ __launch_bounds__(256) void k_fill(const int* __restrict__ ei, const float* __restrict__ ea) {
    int e = blockIdx.x * 256 + threadIdx.x;
    if (e >= NE) return;
    int d = ei[NE + e];
    int pos = atomicAdd(&g_cur[d], 1);
    g_src[pos] = ei[e];
    const float2* s2 = (const float2*)(ea + (size_t)e * 10);
    float2 v0 = s2[0], v1 = s2[1], v2 = s2[2], v3 = s2[3], v4 = s2[4];
    float2* d2 = (float2*)(g_eac + (size_t)pos * 12);
    d2[0] = v0; d2[1] = v1; d2[2] = v2; d2[3] = v3; d2[4] = v4;
    d2[5] = make_float2(0.f, 0.f);
}

// ---------------- lin1: x1 = lrelu(x@W1+b1), xr = x1@att_r ----------------
__global__ __launch_bounds__(256, 4) void k_lin1(const float* __restrict__ x, const float* __restrict__ W1,
                                                 const float* __restrict__ b1, const float* __restrict__ attr_) {
    int n = blockIdx.x * 256 + threadIdx.x;
    if (n >= NN) return;
    const float4* xq4 = (const float4*)(x + (size_t)n * FIN);
    float acc[H];
#pragma unroll
    for (int h = 0; h < H; ++h) acc[h] = 0.f;
#pragma unroll 1
    for (int q = 0; q < FIN / 4; ++q) {
        float4 v = xq4[q];
        const float* wr = W1 + (4 * q) * H;
#pragma unroll
        for (int h = 0; h < H; ++h)
            acc[h] = fmaf(v.x, wr[h], fmaf(v.y, wr[H + h], fmaf(v.z, wr[2 * H + h], fmaf(v.w, wr[3 * H + h], acc[h]))));
    }
    float xrv = 0.f;
    float* xo = g_x1 + (size_t)n * 52;
#pragma unroll
    for (int h = 0; h < H; ++h) {
        float v = lrelu(acc[h] + b1[h]);
        xo[h] = v;
        xrv = fmaf(v, attr_[h], xrv);
    }
    xo[H] = 0.f;
    g_xr[n] = xrv;
}

// ---------------- GATEConv, single pass: wave per dst node, lane = channel ----------------
// Weight column for channel lj held in 16 NAMED float4s (guaranteed registers, no array).
#define MKW(q) make_float4( \
    (4*(q)+0) < 51 ? We1[(4*(q)+0) * H + lj] : 0.f, \
    (4*(q)+1) < 51 ? We1[(4*(q)+1) * H + lj] : 0.f, \
    (4*(q)+2) < 51 ? We1[(4*(q)+2) * H + lj] : 0.f, \
    (4*(q)+3) < 51 ? We1[(4*(q)+3) * H + lj] : 0.f)
#define MKE(q) make_float4( \
    (4*(q)+0) < 10 ? We1[(51 + 4*(q)+0) * H + lj] : 0.f, \
    (4*(q)+1) < 10 ? We1[(51 + 4*(q)+1) * H + lj] : 0.f, \
    (4*(q)+2) < 10 ? We1[(51 + 4*(q)+2) * H + lj] : 0.f, \
    (4*(q)+3) < 10 ? We1[(51 + 4*(q)+3) * H + lj] : 0.f)
// two partial accumulators per edge to halve the FMA dependency chain
#define XE(sv, slot, xout) do { \
    const float4* xp_ = (const float4*)(g_x1 + (size_t)(sv) * 52); \
    const float4* ep_ = (const float4*)(g_eac + (size_t)(slot) * 12); \
    float A_ = 0.f, B_ = 0.f; \
    A_ = d4(A_, xp_[0],  wq0); \
    B_ = d4(B_, xp_[1],  wq1); \
    A_ = d4(A_, xp_[2],  wq2); \
    B_ = d4(B_, xp_[3],  wq3); \
    A_ = d4(A_, xp_[4],  wq4); \
    B_ = d4(B_, xp_[5],  wq5); \
    A_ = d4(A_, xp_[6],  wq6); \
    B_ = d4(B_, xp_[7],  wq7); \
    A_ = d4(A_, xp_[8],  wq8); \
    B_ = d4(B_, xp_[9],  wq9); \
    A_ = d4(A_, xp_[10], wq10); \
    B_ = d4(B_, xp_[11], wq11); \
    A_ = d4(A_, xp_[12], wq12); \
    B_ = d4(B_, ep_[0],  eq0); \
    A_ = d4(A_, ep_[1],  eq1); \
    B_ = d4(B_, ep_[2],  eq2); \
    (xout) = A_ + B_; } while (0)

__global__ __launch_bounds__(256, 4) void k_gate(const float* __restrict__ We1, const float* __restrict__ attl) {
    int lane = threadIdx.x & 63;
    int lj = lane < H ? lane : H - 1;
    int n0 = blockIdx.x * 4 + (threadIdx.x >> 6);
    int n = __builtin_amdgcn_readfirstlane(n0);
    float4 wq0 = MKW(0), wq1 = MKW(1), wq2 = MKW(2), wq3 = MKW(3), wq4 = MKW(4), wq5 = MKW(5),
           wq6 = MKW(6), wq7 = MKW(7), wq8 = MKW(8), wq9 = MKW(9), wq10 = MKW(10), wq11 = MKW(11), wq12 = MKW(12);
    float4 eq0 = MKE(0), eq1 = MKE(1), eq2 = MKE(2);
    float attlv = attl[lj];
    float xrd = g_xr[n];
    int rs = g_rp[n], re = g_rp[n + 1];
    float accH = 0.f, den = 0.f;
    int idx = rs;
    for (; idx + 4 <= re; idx += 4) {
        int s0 = __builtin_amdgcn_readfirstlane(g_src[idx]);
        int s1 = __builtin_amdgcn_readfirstlane(g_src[idx + 1]);
        int s2 = __builtin_amdgcn_readfirstlane(g_src[idx + 2]);
        int s3 = __builtin_amdgcn_readfirstlane(g_src[idx + 3]);
        float xe0, xe1, xe2, xe3;
        XE(s0, idx, xe0);
        XE(s1, idx + 1, xe1);
        XE(s2, idx + 2, xe2);
        XE(s3, idx + 3, xe3);
        float l0 = lrelu(xe0), l1 = lrelu(xe1), l2 = lrelu(xe2), l3 = lrelu(xe3);
        float p0 = (lane < H) ? l0 * attlv : 0.f;
        float p1 = (lane < H) ? l1 * attlv : 0.f;
        float p2 = (lane < H) ? l2 * attlv : 0.f;
        float p3 = (lane < H) ? l3 * attlv : 0.f;
        wave_sum4(p0, p1, p2, p3);
        float e0 = __expf(lrelu(p0 + xrd));
        float e1 = __expf(lrelu(p1 + xrd));
        float e2 = __expf(lrelu(p2 + xrd));
        float e3 = __expf(lrelu(p3 + xrd));
        accH = fmaf(e0, l0, accH); den += e0;
        accH = fmaf(e1, l1, accH); den += e1;
        accH = fmaf(e2, l2, accH); den += e2;
        accH = fmaf(e3, l3, accH); den += e3;
    }
    for (; idx < re; ++idx) {
        int s0 = __builtin_amdgcn_readfirstlane(g_src[idx]);
        float xe0;
        XE(s0, idx, xe0);
        float l0 = lrelu(xe0);
        float a0 = wave_sum((lane < H) ? l0 * attlv : 0.f);
        float e0 = __expf(lrelu(a0 + xrd));
        accH = fmaf(e0, l0, accH); den += e0;
    }
    if (lane < H) g_agg[(size_t)n * H + lane] = accH / (den + 1e-16f);
}

// ---------------- gate(We2) + GRU1 + xl/al fused: wave per node ----------------
__global__ __launch_bounds__(256) void k_gategru(const float* __restrict__ We2, const float* __restrict__ gb,
                                                 const float* __restrict__ Wm, const float* __restrict__ asrc) {
    int lane = threadIdx.x & 63;
    int lj = lane < H ? lane : H - 1;
    int n0 = blockIdx.x * 4 + (threadIdx.x >> 6);
    if (n0 >= NN) return;
    int n = __builtin_amdgcn_readfirstlane(n0);
    const float* aggr = g_agg + (size_t)n * H;
    const float* x1r = g_x1 + (size_t)n * 52;
    float acc = 0.f;
    for (int k = 0; k < H; ++k) acc = fmaf(aggr[k], We2[k * H + lj], acc);
    float hb = elu1(acc + gb[lj]);
    float gir = 0, giz = 0, gin = 0, ghr = 0, ghz = 0, ghn = 0;
    for (int k = 0; k < H; ++k) {
        float hbk = __shfl(hb, k, 64);
        float xk = x1r[k];
        const float4* wp = (const float4*)(g_wg1 + ((size_t)(k * H + lj)) * 8);
        float4 w0 = wp[0];
        float4 w1 = wp[1];
        gir = fmaf(hbk, w0.x, gir); giz = fmaf(hbk, w0.y, giz); gin = fmaf(hbk, w0.z, gin);
        ghr = fmaf(xk, w0.w, ghr);  ghz = fmaf(xk, w1.x, ghz);  ghn = fmaf(xk, w1.y, ghn);
    }
    const float4* bp = (const float4*)(g_bg1 + lane * 8);
    float4 b0 = bp[0];
    float4 b1v = bp[1];
    float r = sigm(gir + b0.x + ghr + b0.w);
    float z = sigm(giz + b0.y + ghz + b1v.x);
    float nn2 = tanhf(gin + b0.z + r * (ghn + b1v.y));
    float xj = x1r[lane];
    float o2 = fmaxf((1.f - z) * nn2 + z * xj, 0.f);
    if (lane < H) g_x2[(size_t)n * H + lane] = o2;
    float xlacc = 0.f;
    for (int k = 0; k < H; ++k) {
        float xk = __shfl(o2, k, 64);
        xlacc = fmaf(xk, Wm[k * H + lj], xlacc);
    }
    if (lane < H) g_xl[(size_t)n * H + lane] = xlacc;
    float v = (lane < H) ? xlacc * asrc[lj] : 0.f;
    v = wave_sum(v);
    if (lane == 0) g_al[n] = v;
}

// ---------------- readout + all 7 timesteps + final linear: wave per graph ----------------
__global__ __launch_bounds__(256) void k_mol_all(const float* __restrict__ mb, const float* __restrict__ W2,
                                                 const float* __restrict__ b2, float* __restrict__ dout) {
    int lane = threadIdx.x & 63;
    int lj = lane < H ? lane : H - 1;
    int b = __builtin_amdgcn_readfirstlane(blockIdx.x * 4 + (threadIdx.x >> 6));
    int gs = g_gs[b], ge = g_gs[b + 1];
    // readout: out0 = relu(sum x2 rows), unrolled by 2
    float oa = 0.f, ob = 0.f;
    int i = gs;
    for (; i + 2 <= ge; i += 2) {
        oa += g_x2[(size_t)i * H + lane];
        ob += g_x2[(size_t)(i + 1) * H + lane];
    }
    if (i < ge) oa += g_x2[(size_t)i * H + lane];
    float oj = fmaxf(oa + ob, 0.f);
    float wvl = g_wv[lane];
    float mbl = mb[lj];
#pragma unroll 1
    for (int t = 0; t < TSTEPS; ++t) {
        float arb = wave_sum((lane < H) ? oj * wvl : 0.f);
        // single fused pass: unnormalized weighted sum + denom, unrolled by 2
        float sa = 0.f, sb = 0.f, aa = 0.f, ab = 0.f;
        i = gs;
        for (; i + 2 <= ge; i += 2) {
            float ev0 = __expf(lrelu(g_al[i] + arb));
            float ev1 = __expf(lrelu(g_al[i + 1] + arb));
            sa += ev0; sb += ev1;
            aa = fmaf(ev0, g_xl[(size_t)i * H + lane], aa);
            ab = fmaf(ev1, g_xl[(size_t)(i + 1) * H + lane], ab);
        }
        if (i < ge) {
            float ev0 = __expf(lrelu(g_al[i] + arb));
            sa += ev0;
            aa = fmaf(ev0, g_xl[(size_t)i * H + lane], aa);
        }
        float inv = 1.f / (sa + sb + 1e-16f);
        float hm = elu1((aa + ab) * inv + mbl);
        // GRU2
        float gir = 0, giz = 0, gin = 0, ghr = 0, ghz = 0, ghn = 0;
        for (int k = 0; k < H; ++k) {
            float hmk = __shfl(hm, k, 64);
            float ok = __shfl(oj, k, 64);
            const float4* wp = (const float4*)(g_wg2 + ((size_t)(k * H + lj)) * 8);
            float4 w0 = wp[0];
            float4 w1 = wp[1];
            gir = fmaf(hmk, w0.x, gir); giz = fmaf(hmk, w0.y, giz); gin = fmaf(hmk, w0.z, gin);
            ghr = fmaf(ok, w0.w, ghr);  ghz = fmaf(ok, w1.x, ghz);  ghn = fmaf(ok, w1.y, ghn);
        }
        const float4* bp = (const float4*)(g_bg2 + lane * 8);
        float4 b0 = bp[0];
        float4 b1v = bp[1];
        float r = sigm(gir + b0.x + ghr + b0.w);
        float z = sigm(giz + b0.y + ghz + b1v.x);
        float nn2 = tanhf(gin + b0.z + r * (ghn + b1v.y));
        oj = fmaxf((1.f - z) * nn2 + z * oj, 0.f);
    }
    float fv = wave_sum((lane < H) ? oj * W2[lj] : 0.f);
    if (lane == 0) dout[b] = fv + b2[0];
}

extern "C" void kernel_launch(void* const* d_in, const int* in_sizes, int n_in,
                              void* d_out, int out_size, void* d_ws, size_t ws_size,
                              hipStream_t stream) {
    const float* x     = (const float*)d_in[0];
    const int*   ei    = (const int*)d_in[1];
    const float* ea    = (const float*)d_in[2];
    const int*   batch = (const int*)d_in[3];
    const float* W1    = (const float*)d_in[4];
    const float* b1    = (const float*)d_in[5];
    const float* We1   = (const float*)d_in[6];
    const float* attl  = (const float*)d_in[7];
    const float* attr_ = (const float*)d_in[8];
    const float* We2   = (const float*)d_in[9];
    const float* gb    = (const float*)d_in[10];
    const float* Wm    = (const float*)d_in[15];
    const float* asrc  = (const float*)d_in[16];
    const float* adst  = (const float*)d_in[17];
    const float* mb    = (const float*)d_in[18];
    const float* W2    = (const float*)d_in[23];
    const float* b2    = (const float*)d_in[24];
    float* dout = (float*)d_out;

    // CSR build
    k_zero<<<SCAN_B, 256, 0, stream>>>();
    k_count<<<NE / 256, 256, 0, stream>>>(ei);
    k_scan1<<<SCAN_B, 256, 0, stream>>>();
    k_scan2<<<1, 512, 0, stream>>>();
    k_scan3<<<SCAN_B, 256, 0, stream>>>();
    k_fill<<<NE / 256, 256, 0, stream>>>(ei, ea);

    // weight prep
    k_pack_gru<<<(H * H + 255) / 256, 256, 0, stream>>>((const float*)d_in[11], (const float*)d_in[12],
                                                        (const float*)d_in[13], (const float*)d_in[14], 0);
    k_pack_gru<<<(H * H + 255) / 256, 256, 0, stream>>>((const float*)d_in[19], (const float*)d_in[20],
                                                        (const float*)d_in[21], (const float*)d_in[22], 1);
    k_wv<<<1, 64, 0, stream>>>(Wm, adst);
    k_gstart<<<(NN + 255) / 256, 256, 0, stream>>>(batch);

    // main pipeline
    k_lin1<<<(NN + 255) / 256, 256, 0, stream>>>(x, W1, b1, attr_);
    k_gate<<<NN / 4, 256, 0, stream>>>(We1, attl);
    k_gategru<<<NN / 4, 256, 0, stream>>>(We2, gb, Wm, asrc);
    k_mol_all<<<NB / 4, 256, 0, stream>>>(mb, W2, b2, dout);
}